// Round 1
// baseline (1632.910 us; speedup 1.0000x reference)
//
#include <hip/hip_runtime.h>
#include <hip/hip_bf16.h>

#define NB 65  // breakpoints; 64 segments

__global__ __launch_bounds__(256) void logsig_pwl_kernel(
    const float4* __restrict__ vals,
    const float*  __restrict__ xs,
    const float*  __restrict__ ys,
    float4*       __restrict__ out,
    int n4)
{
    __shared__ float sx[NB];
    __shared__ float sy[NB];
    __shared__ float sm[NB - 1];

    const int t = threadIdx.x;
    if (t < NB) {
        sx[t] = xs[t];
        sy[t] = ys[t];
    }
    __syncthreads();
    if (t < NB - 1) {
        // slope per segment, matching reference arithmetic (division, fp32)
        sm[t] = (sy[t + 1] - sy[t]) / (sx[t + 1] - sx[t]);
    }
    __syncthreads();

    const float x0    = sx[0];
    const float xK    = sx[NB - 1];
    const float inv_h = 64.0f / (xK - x0);  // uniform grid: 3.2

    const int i = blockIdx.x * blockDim.x + threadIdx.x;
    if (i >= n4) return;

    float4 v = vals[i];
    float4 r;

    float* vp = &v.x;
    float* rp = &r.x;
#pragma unroll
    for (int c = 0; c < 4; ++c) {
        const float val = vp[c];
        int idx = (int)floorf((val - x0) * inv_h);
        idx = idx < 0 ? 0 : (idx > 62 + 1 ? 63 : idx);  // clamp [0,63]
        float interp = sy[idx] + (val - sx[idx]) * sm[idx];
        // v < x[0]  -> identity; v >= x[-1] -> 0
        interp = (val >= xK) ? 0.0f : interp;
        interp = (val < x0)  ? val  : interp;
        rp[c] = interp;
    }

    out[i] = r;
}

extern "C" void kernel_launch(void* const* d_in, const int* in_sizes, int n_in,
                              void* d_out, int out_size, void* d_ws, size_t ws_size,
                              hipStream_t stream) {
    const float* vals = (const float*)d_in[0];
    const float* xs   = (const float*)d_in[1];
    const float* ys   = (const float*)d_in[2];
    float* out        = (float*)d_out;

    const int n  = in_sizes[0];       // 268435456, divisible by 4
    const int n4 = n / 4;

    const int block = 256;
    const int grid  = (n4 + block - 1) / block;

    logsig_pwl_kernel<<<grid, block, 0, stream>>>(
        (const float4*)vals, xs, ys, (float4*)out, n4);
}